// Round 4
// baseline (241.695 us; speedup 1.0000x reference)
//
#include <hip/hip_runtime.h>
#include <math.h>

// (256, 4096, 33) f32 rows: [K, w1[0..31]]; K passes through; w1 gets
// 4x (31-step push-apart scan + clip). One thread per row, row in registers.
//
// Traffic ledger (rocprof, across rounds):
//   R1-R3 DMA-ingest + normal stores : FETCH 67 MB  WRITE 135 MB (slow pipe)
//   R4 normal loads + normal stores  : FETCH 127 MB WRITE 276 MB (LLC churn)
//   R5 nt loads + nt stores          : kernel < 83 us (out of top-5)
// FETCH=67MB in R1-R3 proves the 138 MB input stays LLC-resident across
// bench iterations (the 540 MB poison fills stream to HBM without
// allocating); R1-R3 only lost half of it to their own allocating output
// stores. R5's nt LOADS discarded that residency on purpose -- every input
// byte re-fetched from HBM.
// R6: asymmetric policy. CACHING (default) loads for the input -- it fits
// the 256 MB LLC, is reused every bench iteration, and clean lines evict
// for free. NT stores for the output -- one-touch, no LLC allocation, so
// it cannot churn the input residency (R4's failure mode).
// Predicted: FETCH <= 67 MB, WRITE ~138 MB, kernel ~30-45 us.
//
// Structure (R4): reg-staged pipeline, 1-wave blocks, no barriers.
//   loads(t+1) in flight under compute(t); ds_write staging waits on
//   counted vmcnt; single 8.4 KB LDS buffer (per-wave in-order DS pipe
//   makes WAR safe); row stride 33 -> 2-way bank aliasing (free, m136).

#define THREADS 64
#define ROW 33
#define TROWS 64                  // rows per tile (= one wave)
#define FPT (TROWS * ROW)         // 2112 floats per tile (8448 B)
#define V4PT (FPT / 4)            // 528 float4 per tile
#define TAIL (V4PT - 8 * THREADS) // 16-lane ragged tail
#define GRID 4096                 // 16 blocks/CU, 4 tiles per block

typedef __attribute__((ext_vector_type(4))) float v4f;

__global__ __launch_bounds__(THREADS) void lsp_stability_kernel(
    const float* __restrict__ in, float* __restrict__ out, int tiles)
{
    __shared__ alignas(16) float smem[FPT];
    const int tid = threadIdx.x;
    const int bid = blockIdx.x;
    if (bid >= tiles) return;
    const int grid = (int)gridDim.x;
    const int nt = (tiles - bid + grid - 1) / grid;   // tiles for this block

    const float MIND = (float)(0.01 * M_PI / 33.0);   // RATE*pi/(ORDER+1)
    const float PI_F = (float)M_PI;
    const float HI = PI_F - MIND;

    v4f* s4 = (v4f*)smem;
    v4f r[9];                     // 36 VGPRs of staging, statically indexed

    // Prologue: issue tile 0's loads; consumed by first staging ds_write.
    {
        const v4f* g4 = (const v4f*)(in + (size_t)bid * FPT);
#pragma unroll
        for (int j = 0; j < 8; ++j) r[j] = g4[tid + j * THREADS];
        if (tid < TAIL) r[8] = g4[tid + 8 * THREADS];
    }

    for (int t = 0; t < nt; ++t) {
        const size_t tile = (size_t)bid + (size_t)t * grid;

        // Stage tile t: regs -> LDS (compiler inserts counted vmcnt per r[j]).
#pragma unroll
        for (int j = 0; j < 8; ++j) s4[tid + j * THREADS] = r[j];
        if (tid < TAIL) s4[tid + 8 * THREADS] = r[8];

        // Issue tile t+1's loads now; they drain under the compute below
        // and are next consumed at the TOP of the next iteration.
        if (t + 1 < nt) {
            const v4f* g4 = (const v4f*)(in + (tile + grid) * FPT);
#pragma unroll
            for (int j = 0; j < 8; ++j) r[j] = g4[tid + j * THREADS];
            if (tid < TAIL) r[8] = g4[tid + 8 * THREADS];
        }

        // Each thread owns one row; w1 (32 elems) in registers. Same-wave
        // ds_write -> ds_read needs no barrier (in-order per-wave DS pipe;
        // compiler orders via lgkmcnt).
        float w[32];
        float* row = smem + tid * ROW;
#pragma unroll
        for (int k = 0; k < 32; ++k) w[k] = row[k + 1];

#pragma unroll
        for (int it = 0; it < 4; ++it) {
            float c = w[0];
#pragma unroll
            for (int k = 1; k < 32; ++k) {
                float nxt = w[k];
                float sft = 0.5f * fmaxf(MIND - (nxt - c), 0.0f);
                w[k - 1] = c - sft;   // 0.5*m exact (pow2 mul) -> fma-safe
                c = nxt + sft;
            }
            w[31] = c;
#pragma unroll
            for (int k = 0; k < 32; ++k)
                w[k] = fminf(fmaxf(w[k], MIND), HI);
        }

        // K (element 0) untouched in LDS; write back w1 only.
#pragma unroll
        for (int k = 0; k < 32; ++k) row[k + 1] = w[k];

        // Coalesced LDS -> global nt store (ds_read_b128 + store_dwordx4 nt).
        // Next iteration's staging ds_writes are ordered after these
        // ds_reads by the in-order DS pipe -> single buffer is WAR-safe.
        v4f* out4 = (v4f*)(out + tile * FPT);
#pragma unroll
        for (int j = 0; j < 8; ++j)
            __builtin_nontemporal_store(s4[tid + j * THREADS],
                                        out4 + tid + j * THREADS);
        if (tid < TAIL)
            __builtin_nontemporal_store(s4[tid + 8 * THREADS],
                                        out4 + tid + 8 * THREADS);
    }
}

extern "C" void kernel_launch(void* const* d_in, const int* in_sizes, int n_in,
                              void* d_out, int out_size, void* d_ws, size_t ws_size,
                              hipStream_t stream) {
    const float* in = (const float*)d_in[0];
    float* out = (float*)d_out;
    // total = 256*4096*33 = 34,603,008 floats; 2112 per tile -> 16384 tiles.
    const int tiles = in_sizes[0] / FPT;
    const int blocks = tiles < GRID ? tiles : GRID;   // 4096 -> 4 tiles/block
    lsp_stability_kernel<<<blocks, THREADS, 0, stream>>>(in, out, tiles);
}

// Round 5
// 229.451 us; speedup vs baseline: 1.0534x; 1.0534x over previous
//
#include <hip/hip_runtime.h>
#include <math.h>

// (256, 4096, 33) f32 rows: [K, w1[0..31]]; K passes through; w1 gets
// 4x (31-step push-apart scan + clip). One thread per row, row in registers.
//
// Traffic/time ledger (rocprof, six rounds):
//   R1-R3 DMA ingest + normal stores : 84 us, FETCH 67 MB (half input LLC)
//   R4 cached loads + cached stores  : 104 us, FETCH 127, WRITE 276 (churn)
//   R5 nt loads + nt stores          : <83 us (out of top-5; best bench)
//   R6 cached loads + nt stores      : 84 us, FETCH 67 MB -- == R1-R3!
// Law: ingest path doesn't matter (DMA == cached vector loads, both 84 us,
// both FETCH=67MB); what matters is LLC involvement. Reads that hit/allocate
// in the MALL run ~2.5 TB/s; nt streaming reads from HBM are faster. The
// MALL is memory-side -- its hit path doesn't amplify BW. So: nt loads AND
// nt stores (R5 policy).
// Second defect (rocprof): VGPR_Count=44 in R4/R6 -- r[9](36)+w[32] can't
// coexist -> compiler SANK the t+1 prefetch loads to after compute, exposing
// full HBM latency per tile. R5 had the same defect.
// R7 = R5 + prefetch retention: __launch_bounds__(64,4) caps occupancy at
// 16 blocks/CU (4 waves/EU) -> 128-VGPR budget, enough for r[9]+w[32];
// sched_barrier(0) after the prefetch-issue block stops the sink. Staging
// then waits on a counted vmcnt (9 nt stores outstanding), loads stream
// under compute.

#define THREADS 64
#define ROW 33
#define TROWS 64                  // rows per tile (= one wave)
#define FPT (TROWS * ROW)         // 2112 floats per tile (8448 B)
#define V4PT (FPT / 4)            // 528 float4 per tile
#define TAIL (V4PT - 8 * THREADS) // 16-lane ragged tail
#define GRID 4096                 // 16 blocks/CU resident, 4 tiles per block

typedef __attribute__((ext_vector_type(4))) float v4f;

__global__ __launch_bounds__(THREADS, 4) void lsp_stability_kernel(
    const float* __restrict__ in, float* __restrict__ out, int tiles)
{
    __shared__ alignas(16) float smem[FPT];
    const int tid = threadIdx.x;
    const int bid = blockIdx.x;
    if (bid >= tiles) return;
    const int grid = (int)gridDim.x;
    const int nt = (tiles - bid + grid - 1) / grid;   // tiles for this block

    const float MIND = (float)(0.01 * M_PI / 33.0);   // RATE*pi/(ORDER+1)
    const float PI_F = (float)M_PI;
    const float HI = PI_F - MIND;

    v4f* s4 = (v4f*)smem;
    v4f r[9];                     // 36 VGPRs of staging, statically indexed

    // Prologue: issue tile 0's loads; consumed by first staging ds_write.
    {
        const v4f* g4 = (const v4f*)(in + (size_t)bid * FPT);
#pragma unroll
        for (int j = 0; j < 8; ++j)
            r[j] = __builtin_nontemporal_load(g4 + tid + j * THREADS);
        if (tid < TAIL)
            r[8] = __builtin_nontemporal_load(g4 + tid + 8 * THREADS);
    }

    for (int t = 0; t < nt; ++t) {
        const size_t tile = (size_t)bid + (size_t)t * grid;

        // Stage tile t: regs -> LDS (compiler emits counted vmcnt per r[j];
        // the 9 in-flight nt stores of tile t-1 need not drain).
#pragma unroll
        for (int j = 0; j < 8; ++j) s4[tid + j * THREADS] = r[j];
        if (tid < TAIL) s4[tid + 8 * THREADS] = r[8];

        // Issue tile t+1's loads NOW; sched_barrier(0) pins them here so
        // they drain under the ~2000-cycle compute below instead of being
        // sunk past it (the R4/R6 VGPR=44 failure mode).
        if (t + 1 < nt) {
            const v4f* g4 = (const v4f*)(in + (tile + grid) * FPT);
#pragma unroll
            for (int j = 0; j < 8; ++j)
                r[j] = __builtin_nontemporal_load(g4 + tid + j * THREADS);
            if (tid < TAIL)
                r[8] = __builtin_nontemporal_load(g4 + tid + 8 * THREADS);
        }
        __builtin_amdgcn_sched_barrier(0);

        // Each thread owns one row; w1 (32 elems) in registers. Same-wave
        // ds_write -> ds_read needs no barrier (in-order per-wave DS pipe;
        // compiler orders via lgkmcnt). Row stride 33 -> 2-way bank
        // aliasing across wave64 (free, m136).
        float w[32];
        float* row = smem + tid * ROW;
#pragma unroll
        for (int k = 0; k < 32; ++k) w[k] = row[k + 1];

#pragma unroll
        for (int it = 0; it < 4; ++it) {
            float c = w[0];
#pragma unroll
            for (int k = 1; k < 32; ++k) {
                float nxt = w[k];
                float sft = 0.5f * fmaxf(MIND - (nxt - c), 0.0f);
                w[k - 1] = c - sft;   // 0.5*m exact (pow2 mul) -> fma-safe
                c = nxt + sft;
            }
            w[31] = c;
#pragma unroll
            for (int k = 0; k < 32; ++k)
                w[k] = fminf(fmaxf(w[k], MIND), HI);
        }

        // K (element 0) untouched in LDS; write back w1 only.
#pragma unroll
        for (int k = 0; k < 32; ++k) row[k + 1] = w[k];

        // Coalesced LDS -> global nt store (ds_read_b128 + store_dwordx4 nt).
        // Next iteration's staging ds_writes are ordered after these
        // ds_reads by the in-order DS pipe -> single buffer is WAR-safe.
        v4f* out4 = (v4f*)(out + tile * FPT);
#pragma unroll
        for (int j = 0; j < 8; ++j)
            __builtin_nontemporal_store(s4[tid + j * THREADS],
                                        out4 + tid + j * THREADS);
        if (tid < TAIL)
            __builtin_nontemporal_store(s4[tid + 8 * THREADS],
                                        out4 + tid + 8 * THREADS);
    }
}

extern "C" void kernel_launch(void* const* d_in, const int* in_sizes, int n_in,
                              void* d_out, int out_size, void* d_ws, size_t ws_size,
                              hipStream_t stream) {
    const float* in = (const float*)d_in[0];
    float* out = (float*)d_out;
    // total = 256*4096*33 = 34,603,008 floats; 2112 per tile -> 16384 tiles.
    const int tiles = in_sizes[0] / FPT;
    const int blocks = tiles < GRID ? tiles : GRID;   // 4096 -> 4 tiles/block
    lsp_stability_kernel<<<blocks, THREADS, 0, stream>>>(in, out, tiles);
}

// Round 6
// 227.820 us; speedup vs baseline: 1.0609x; 1.0072x over previous
//
#include <hip/hip_runtime.h>
#include <math.h>

// (256, 4096, 33) f32 rows: [K, w1[0..31]]; K passes through; w1 gets
// 4x (31-step push-apart scan + clip). One thread per row, row in registers.
//
// Policy-quadrant ledger (kernel time; bench - ~156 us fixed overhead):
//   cached loads + cached stores : 84-104 us (R1-R4; LLC on critical path)
//   cached loads + nt stores     : 84 us      (R6)
//   nt loads     + nt stores     : ~73 us     (R5/R7; 3.8 TB/s)
//   nt loads     + cached stores : THIS ROUND
// R7 (launch_bounds + sched_barrier prefetch pin) == R5 exactly -> the
// kernel is not latency/concurrency-limited (exposed-miss arithmetic says
// ~5 us total at 16 waves/CU); it's path-limited. nt/nt only reaches
// 3.8 TB/s -- likely HBM read/write turnaround with both streams on the
// bus (m13's cached copy does 6.3 TB/s on the same mix via MALL write
// scheduling). R8 mechanism: input bypasses LLC (nt) -> MALL empty ->
// 138 MB output allocates churn-free, stores complete at MALL speed,
// writeback defers off the kernel's clock; kernel's HBM bus is ~pure
// reads at full streaming rate.
// Predicted: kernel ~35-55 us, FETCH ~138 MB, WRITE <= 138 MB (partially
// outside the dispatch window). Falsifier: bench ~240 (kernel 84) =>
// cached-store leg has the same LLC serialization; nt/nt is the floor.
//
// Structure: reg-staged pipeline, 1-wave blocks, no barriers; loads(t+1)
// issued before compute(t) (sched_barrier pins them); single 8.4 KB LDS
// buffer (per-wave in-order DS pipe -> WAR-safe); row stride 33 -> 2-way
// bank aliasing (free, m136).

#define THREADS 64
#define ROW 33
#define TROWS 64                  // rows per tile (= one wave)
#define FPT (TROWS * ROW)         // 2112 floats per tile (8448 B)
#define V4PT (FPT / 4)            // 528 float4 per tile
#define TAIL (V4PT - 8 * THREADS) // 16-lane ragged tail
#define GRID 4096                 // 16 blocks/CU resident, 4 tiles per block

typedef __attribute__((ext_vector_type(4))) float v4f;

__global__ __launch_bounds__(THREADS, 4) void lsp_stability_kernel(
    const float* __restrict__ in, float* __restrict__ out, int tiles)
{
    __shared__ alignas(16) float smem[FPT];
    const int tid = threadIdx.x;
    const int bid = blockIdx.x;
    if (bid >= tiles) return;
    const int grid = (int)gridDim.x;
    const int nt = (tiles - bid + grid - 1) / grid;   // tiles for this block

    const float MIND = (float)(0.01 * M_PI / 33.0);   // RATE*pi/(ORDER+1)
    const float PI_F = (float)M_PI;
    const float HI = PI_F - MIND;

    v4f* s4 = (v4f*)smem;
    v4f r[9];                     // 36 VGPRs of staging, statically indexed

    // Prologue: issue tile 0's loads; consumed by first staging ds_write.
    {
        const v4f* g4 = (const v4f*)(in + (size_t)bid * FPT);
#pragma unroll
        for (int j = 0; j < 8; ++j)
            r[j] = __builtin_nontemporal_load(g4 + tid + j * THREADS);
        if (tid < TAIL)
            r[8] = __builtin_nontemporal_load(g4 + tid + 8 * THREADS);
    }

    for (int t = 0; t < nt; ++t) {
        const size_t tile = (size_t)bid + (size_t)t * grid;

        // Stage tile t: regs -> LDS (compiler emits counted vmcnt per r[j]).
#pragma unroll
        for (int j = 0; j < 8; ++j) s4[tid + j * THREADS] = r[j];
        if (tid < TAIL) s4[tid + 8 * THREADS] = r[8];

        // Issue tile t+1's loads NOW; sched_barrier(0) pins them above the
        // compute so they drain underneath it.
        if (t + 1 < nt) {
            const v4f* g4 = (const v4f*)(in + (tile + grid) * FPT);
#pragma unroll
            for (int j = 0; j < 8; ++j)
                r[j] = __builtin_nontemporal_load(g4 + tid + j * THREADS);
            if (tid < TAIL)
                r[8] = __builtin_nontemporal_load(g4 + tid + 8 * THREADS);
        }
        __builtin_amdgcn_sched_barrier(0);

        // Each thread owns one row; w1 (32 elems) in registers. Same-wave
        // ds_write -> ds_read needs no barrier (in-order per-wave DS pipe;
        // compiler orders via lgkmcnt).
        float w[32];
        float* row = smem + tid * ROW;
#pragma unroll
        for (int k = 0; k < 32; ++k) w[k] = row[k + 1];

#pragma unroll
        for (int it = 0; it < 4; ++it) {
            float c = w[0];
#pragma unroll
            for (int k = 1; k < 32; ++k) {
                float nxt = w[k];
                float sft = 0.5f * fmaxf(MIND - (nxt - c), 0.0f);
                w[k - 1] = c - sft;   // 0.5*m exact (pow2 mul) -> fma-safe
                c = nxt + sft;
            }
            w[31] = c;
#pragma unroll
            for (int k = 0; k < 32; ++k)
                w[k] = fminf(fmaxf(w[k], MIND), HI);
        }

        // K (element 0) untouched in LDS; write back w1 only.
#pragma unroll
        for (int k = 0; k < 32; ++k) row[k + 1] = w[k];

        // Coalesced LDS -> global CACHED store (the quadrant under test):
        // output allocates in the otherwise-empty MALL, writeback deferred.
        v4f* out4 = (v4f*)(out + tile * FPT);
#pragma unroll
        for (int j = 0; j < 8; ++j)
            out4[tid + j * THREADS] = s4[tid + j * THREADS];
        if (tid < TAIL)
            out4[tid + 8 * THREADS] = s4[tid + 8 * THREADS];
    }
}

extern "C" void kernel_launch(void* const* d_in, const int* in_sizes, int n_in,
                              void* d_out, int out_size, void* d_ws, size_t ws_size,
                              hipStream_t stream) {
    const float* in = (const float*)d_in[0];
    float* out = (float*)d_out;
    // total = 256*4096*33 = 34,603,008 floats; 2112 per tile -> 16384 tiles.
    const int tiles = in_sizes[0] / FPT;
    const int blocks = tiles < GRID ? tiles : GRID;   // 4096 -> 4 tiles/block
    lsp_stability_kernel<<<blocks, THREADS, 0, stream>>>(in, out, tiles);
}

// Round 7
// 227.750 us; speedup vs baseline: 1.0612x; 1.0003x over previous
//
#include <hip/hip_runtime.h>
#include <math.h>

// (256, 4096, 33) f32 rows: [K, w1[0..31]]; K passes through; w1 gets
// 4x (31-step push-apart scan + clip). One thread per row, row in registers.
//
// Ledger through R8 (kernel time = bench - ~157 us fixed harness overhead):
//   R4 cached/cached : 407 MB / 104 us = 3.9 TB/s
//   R5/R7 nt/nt      : 276 MB / ~73 us = 3.8 TB/s
//   R8 nt/cached     : 276 MB / ~71 us = 3.9 TB/s  <- best bench 227.8
// Bus rate is a STRUCTURAL constant ~3.9 TB/s across all policies; m13's
// float4 copy does 6.29 TB/s combined on the same R/W mix. R7's null
// (prefetch retention == no prefetch) rules out per-wave latency exposure.
// Remaining structural difference vs the 6.3-6.6 TB/s references (fills,
// m13): they saturate via BLOCK CHURN (oversubscribed one-shot blocks,
// uncorrelated load bursts, no loop-carried vmcnt coupling); our persistent
// waves self-couple load->stage->compute->store->load across tiles.
// R9: one-shot blocks. grid=16384 (1 tile/block), no loop, no prefetch:
//   9 nt loads -> LDS -> compute -> 9 CACHED stores -> exit.
// nt loads: input must not displace LLC (proven R5/R8 >= cached).
// cached stores: fast MALL ack -> fast s_endpgm vmcnt drain -> fast block
// exit -> higher churn (nt stores would park the wave at exit; R8 edged R5).
// LDS 8.7 KB -> 18 resident blocks/CU, CP backfills continuously.
// Predicted: kernel ~45-60 us visible in top-5, hbm ~4.5-6 TB/s,
// FETCH~135 WRITE~135 MB, Occupancy ~50%+; bench ~203-217.
// Falsifier: ~72 us again => 3.9 TB/s is pattern-intrinsic => roofline.

#define THREADS 64
#define ROW 33
#define TROWS 64                  // rows per tile (= one wave = one block)
#define FPT (TROWS * ROW)         // 2112 floats per tile (8448 B)
#define V4PT (FPT / 4)            // 528 float4 per tile
#define TAIL (V4PT - 8 * THREADS) // 16-lane ragged tail

typedef __attribute__((ext_vector_type(4))) float v4f;

__global__ __launch_bounds__(THREADS) void lsp_stability_kernel(
    const float* __restrict__ in, float* __restrict__ out)
{
    __shared__ alignas(16) float smem[FPT];
    const int tid = threadIdx.x;
    const size_t base = (size_t)blockIdx.x * FPT;

    const float MIND = (float)(0.01 * M_PI / 33.0);   // RATE*pi/(ORDER+1)
    const float PI_F = (float)M_PI;
    const float HI = PI_F - MIND;

    // Ingest: 9 nt loads (bypass LLC) -> regs -> LDS. Compiler emits
    // counted vmcnt per r[j]; nothing older to wait behind (fresh block).
    v4f* s4 = (v4f*)smem;
    {
        const v4f* g4 = (const v4f*)(in + base);
        v4f r[9];
#pragma unroll
        for (int j = 0; j < 8; ++j)
            r[j] = __builtin_nontemporal_load(g4 + tid + j * THREADS);
        if (tid < TAIL)
            r[8] = __builtin_nontemporal_load(g4 + tid + 8 * THREADS);
#pragma unroll
        for (int j = 0; j < 8; ++j) s4[tid + j * THREADS] = r[j];
        if (tid < TAIL) s4[tid + 8 * THREADS] = r[8];
    }

    // Each thread owns one row; w1 (32 elems) in registers. Same-wave
    // ds_write -> ds_read needs no barrier (in-order per-wave DS pipe;
    // compiler orders via lgkmcnt). Row stride 33 -> 2-way bank aliasing
    // across wave64 (free, m136).
    float w[32];
    float* row = smem + tid * ROW;
#pragma unroll
    for (int k = 0; k < 32; ++k) w[k] = row[k + 1];

#pragma unroll
    for (int it = 0; it < 4; ++it) {
        float c = w[0];
#pragma unroll
        for (int k = 1; k < 32; ++k) {
            float nxt = w[k];
            float sft = 0.5f * fmaxf(MIND - (nxt - c), 0.0f);
            w[k - 1] = c - sft;   // 0.5*m exact (pow2 mul) -> fma-safe
            c = nxt + sft;
        }
        w[31] = c;
#pragma unroll
        for (int k = 0; k < 32; ++k)
            w[k] = fminf(fmaxf(w[k], MIND), HI);
    }

    // K (element 0) untouched in LDS; write back w1 only.
#pragma unroll
    for (int k = 0; k < 32; ++k) row[k + 1] = w[k];

    // Egress: coalesced LDS -> global CACHED stores (fast MALL ack ->
    // fast exit -> block churn keeps the read stream dense).
    v4f* out4 = (v4f*)(out + base);
#pragma unroll
    for (int j = 0; j < 8; ++j)
        out4[tid + j * THREADS] = s4[tid + j * THREADS];
    if (tid < TAIL)
        out4[tid + 8 * THREADS] = s4[tid + 8 * THREADS];
}

extern "C" void kernel_launch(void* const* d_in, const int* in_sizes, int n_in,
                              void* d_out, int out_size, void* d_ws, size_t ws_size,
                              hipStream_t stream) {
    const float* in = (const float*)d_in[0];
    float* out = (float*)d_out;
    // total = 256*4096*33 = 34,603,008 floats; 2112 per tile -> 16384
    // one-shot blocks (1 tile each).
    const int blocks = in_sizes[0] / FPT;
    lsp_stability_kernel<<<blocks, THREADS, 0, stream>>>(in, out);
}